// Round 1
// baseline (1244.470 us; speedup 1.0000x reference)
//
#include <hip/hip_runtime.h>
#include <hip/hip_bf16.h>

#define S_ 16
#define N_ 64
#define D_ 1270
#define F_ 150
#define LOSS_OFF (S_*N_*N_*8)   // 524288

constexpr int KC  = 64;
constexpr int NCH = (D_ + KC - 1) / KC;   // 20 (last chunk = 54)
constexpr int AP  = 68;                   // bufA row stride (floats), 16B-aligned rows, conflict-light

__global__ __launch_bounds__(256, 2)
void relscores_kernel(const float* __restrict__ emb,    // [S][N][D]
                      const float* __restrict__ esc,    // [S][N]
                      const float* __restrict__ Win,    // [3D][F]
                      const float* __restrict__ bin,    // [F]
                      const float* __restrict__ Wh,     // [F][F]
                      const float* __restrict__ bhv,    // [F]
                      const float* __restrict__ Wout,   // [F][7]
                      const float* __restrict__ bout,   // [7]
                      const int*   __restrict__ labels, // [S][N][N]
                      const int*   __restrict__ nump,   // [S]
                      float* __restrict__ out)          // rel_scores flat + loss
{
    __shared__ float ej[D_];                 // e_j row
    __shared__ float bufA[KC][AP];           // E chunk, d-major  (later: Wh chunk / scores buf)
    __shared__ float bufB[KC*F_ + 16];       // B' chunk (later: h, then h2)
    __shared__ float cvec[F_];               // P2[j] + b_in

    const int bid = blockIdx.x;
    const int s   = bid >> 6;
    const int j   = bid & 63;
    const int tid = threadIdx.x;
    const int tx  = tid & 31;    // f = tx + 32q
    const int ty  = tid >> 5;    // i = ty*8 + r

    // ---- stage e_j ----
    const float* ejsrc = emb + (size_t)(s*N_ + j) * D_;
    for (int idx = tid; idx < D_; idx += 256) ej[idx] = ejsrc[idx];
    __syncthreads();

    // ---- cvec = b_in + sum_d e_j[d]*W2[d,f]  (threads 0..149) ----
    if (tid < F_) {
        float sum = bin[tid];
        const float* w2 = Win + (size_t)D_ * F_ + tid;
        #pragma unroll 4
        for (int d = 0; d < D_; ++d) sum += ej[d] * w2[(size_t)d * F_];
        cvec[tid] = sum;
    }

    // ---- GEMM1: h_part[i,f] = sum_d E[i,d] * (W1[d,f] + ej[d]*W3[d,f]) ----
    float acc[8][5];
    #pragma unroll
    for (int r = 0; r < 8; ++r)
        #pragma unroll
        for (int q = 0; q < 5; ++q) acc[r][q] = 0.f;

    const int irow = tid >> 2;          // 0..63
    const int part = tid & 3;           // 0..3
    const float* esrc = emb + (size_t)(s*N_ + irow) * D_;

    for (int c = 0; c < NCH; ++c) {
        const int d0 = c * KC;
        // load E chunk transposed: bufA[dk][i]   (float2: rows are only 8B aligned)
        #pragma unroll
        for (int u = 0; u < 8; ++u) {
            int dk = part*16 + u*2;
            int d  = d0 + dk;
            float2 v = make_float2(0.f, 0.f);
            if (d + 1 < D_)      v = *(const float2*)(esrc + d);
            else if (d < D_)     v.x = esrc[d];
            bufA[dk][irow]   = v.x;
            bufA[dk+1][irow] = v.y;
        }
        // build B'[dk][f] = W1[d,f] + ej[d]*W3[d,f]   (zero for d >= D_)
        for (int idx = tid; idx < KC*F_; idx += 256) {
            int dk = idx / F_;
            int f  = idx - dk*F_;
            int d  = d0 + dk;
            float b = 0.f;
            if (d < D_)
                b = Win[(size_t)d * F_ + f] + ej[d] * Win[((size_t)(2*D_) + d) * F_ + f];
            bufB[idx] = b;
        }
        __syncthreads();

        #pragma unroll 2
        for (int dk = 0; dk < KC; ++dk) {
            const float4 a0 = *(const float4*)&bufA[dk][ty*8];
            const float4 a1 = *(const float4*)&bufA[dk][ty*8 + 4];
            const float* bp = &bufB[dk*F_ + tx];
            const float av[8] = {a0.x,a0.y,a0.z,a0.w,a1.x,a1.y,a1.z,a1.w};
            const float wv[5] = {bp[0], bp[32], bp[64], bp[96], bp[128]};
            #pragma unroll
            for (int r = 0; r < 8; ++r)
                #pragma unroll
                for (int q = 0; q < 5; ++q)
                    acc[r][q] += av[r] * wv[q];
        }
        __syncthreads();
    }

    // ---- h = acc + cvec  -> bufB (64 x 150) ----
    #pragma unroll
    for (int r = 0; r < 8; ++r)
        #pragma unroll
        for (int q = 0; q < 5; ++q) {
            int f = tx + 32*q;
            if (f < F_) bufB[(ty*8 + r)*F_ + f] = acc[r][q] + cvec[f];
        }
    __syncthreads();

    // ---- GEMM2: h2 = h @ Wh + bh ----
    float acc2[8][5];
    #pragma unroll
    for (int r = 0; r < 8; ++r)
        #pragma unroll
        for (int q = 0; q < 5; ++q) acc2[r][q] = 0.f;

    float* wbuf = (float*)bufA;   // 25*150 = 3750 <= 64*68
    for (int c2 = 0; c2 < 6; ++c2) {
        const int k0 = c2 * 25;
        for (int idx = tid; idx < 25*F_; idx += 256) {
            int dk = idx / F_;
            int f  = idx - dk*F_;
            wbuf[idx] = Wh[(size_t)(k0 + dk) * F_ + f];
        }
        __syncthreads();
        for (int dk = 0; dk < 25; ++dk) {
            const int k = k0 + dk;
            float av[8];
            #pragma unroll
            for (int r = 0; r < 8; ++r) av[r] = bufB[(ty*8 + r)*F_ + k];
            const float* bp = &wbuf[dk*F_ + tx];
            const float wv[5] = {bp[0], bp[32], bp[64], bp[96], bp[128]};
            #pragma unroll
            for (int r = 0; r < 8; ++r)
                #pragma unroll
                for (int q = 0; q < 5; ++q)
                    acc2[r][q] += av[r] * wv[q];
        }
        __syncthreads();
    }
    // write h2 -> bufB
    #pragma unroll
    for (int r = 0; r < 8; ++r)
        #pragma unroll
        for (int q = 0; q < 5; ++q) {
            int f = tx + 32*q;
            if (f < F_) bufB[(ty*8 + r)*F_ + f] = acc2[r][q] + bhv[f];
        }
    __syncthreads();

    // ---- GEMM3: scores[i,l] = h2[i,:] @ Wout[:,l] + bout[l] ----
    float* sbuf = (float*)bufA;   // 64*7
    {
        const int i3 = tid & 63;
        const int lg = tid >> 6;           // 0..3
        const int l0 = lg, l1 = lg + 4;    // l1 valid if lg<3
        float s0 = bout[l0];
        float s1 = (l1 < 7) ? bout[l1] : 0.f;
        const float* hrow = &bufB[i3 * F_];
        #pragma unroll 2
        for (int k = 0; k < F_; ++k) {
            const float hv = hrow[k];
            s0 += hv * Wout[k*7 + l0];
            if (l1 < 7) s1 += hv * Wout[k*7 + l1];
        }
        sbuf[i3*7 + l0] = s0;
        if (l1 < 7) sbuf[i3*7 + l1] = s1;
    }
    __syncthreads();

    // ---- epilogue: rel_scores write, log-softmax CE, masked loss ----
    if (tid < 64) {
        const int i = tid;
        const float esi = esc[s*N_ + i];
        const float esj = esc[s*N_ + j];
        float r[8];
        r[0] = 0.f;
        #pragma unroll
        for (int l = 1; l < 8; ++l) r[l] = sbuf[i*7 + (l-1)] + esi + esj;

        float4* op = (float4*)(out + ((size_t)(s*N_ + i)*N_ + j) * 8);
        op[0] = make_float4(r[0], r[1], r[2], r[3]);
        op[1] = make_float4(r[4], r[5], r[6], r[7]);

        float m = r[0];
        #pragma unroll
        for (int l = 1; l < 8; ++l) m = fmaxf(m, r[l]);
        float sum = 0.f;
        #pragma unroll
        for (int l = 0; l < 8; ++l) sum += expf(r[l] - m);
        const float lse = m + logf(sum);

        const int lab = labels[(s*N_ + i)*N_ + j];
        float ce = lse - r[lab];
        const int np = nump[s];
        float v = (i < np && j < np) ? ce : 0.f;
        #pragma unroll
        for (int off = 32; off; off >>= 1) v += __shfl_down(v, off);
        if (tid == 0) atomicAdd(out + LOSS_OFF, v);
    }
}

extern "C" void kernel_launch(void* const* d_in, const int* in_sizes, int n_in,
                              void* d_out, int out_size, void* d_ws, size_t ws_size,
                              hipStream_t stream) {
    const float* emb  = (const float*)d_in[0];
    const float* esc  = (const float*)d_in[1];
    const float* Win  = (const float*)d_in[2];
    const float* bin  = (const float*)d_in[3];
    const float* Wh   = (const float*)d_in[4];
    const float* bh   = (const float*)d_in[5];
    const float* Wout = (const float*)d_in[6];
    const float* bout = (const float*)d_in[7];
    const int* labels = (const int*)d_in[8];
    const int* nump   = (const int*)d_in[9];
    float* out = (float*)d_out;

    // zero the loss accumulator slot (rel_scores is fully overwritten each call)
    hipMemsetAsync(out + LOSS_OFF, 0, sizeof(float), stream);

    hipLaunchKernelGGL(relscores_kernel, dim3(S_*N_), dim3(256), 0, stream,
                       emb, esc, Win, bin, Wh, bh, Wout, bout, labels, nump, out);
}

// Round 2
// 185.500 us; speedup vs baseline: 6.7087x; 6.7087x over previous
//
#include <hip/hip_runtime.h>
#include <hip/hip_bf16.h>
#include <stdint.h>

typedef __attribute__((ext_vector_type(8))) short bf16x8;
typedef __attribute__((ext_vector_type(16))) float f32x16;

#define S_ 16
#define N_ 64
#define D_ 1270
#define F_ 150
#define KP_ 1280
#define FP_ 160
#define NKT 80
#define LOSS_OFF (S_*N_*N_*8)

// ---------- helpers ----------
__device__ inline short f2b(float x) {              // f32 -> bf16 (RNE)
    union { float f; uint32_t u; } v; v.f = x;
    uint32_t r = (v.u + 0x7fffu + ((v.u >> 16) & 1u)) >> 16;
    return (short)r;
}

// ---------- pack E into A-frag layout (bf16) ----------
// EApk[s][kt][mt][lane][u] : i=(lane&31)+mt*32, k=kt*16+(lane>>5)*8+u
__global__ void k_pack_ea(const float* __restrict__ emb, short* __restrict__ eapk) {
    int t = blockIdx.x * 256 + threadIdx.x;
    const int TOT = S_ * NKT * 2 * 64;
    if (t >= TOT) return;
    int l  = t & 63;
    int mt = (t >> 6) & 1;
    int kt = (t >> 7) % NKT;
    int s  = t / (NKT * 2 * 64);
    int i  = (l & 31) + mt * 32;
    int k0 = kt * 16 + (l >> 5) * 8;
    const float* src = emb + (size_t)(s * N_ + i) * D_;
    bf16x8 pk;
    #pragma unroll
    for (int u = 0; u < 8; ++u) {
        int k = k0 + u;
        pk[u] = (k < D_) ? f2b(src[k]) : (short)0;
    }
    *(bf16x8*)(eapk + (size_t)t * 8) = pk;
}

// ---------- pack W3 / [W1|W2] / Wh into B-frag layout (bf16) ----------
// B-frag: col=(lane&31)+nt*32, k=kt*16+(lane>>5)*8+u
__global__ void k_pack_w(const float* __restrict__ win, const float* __restrict__ wh,
                         short* __restrict__ w3pk, short* __restrict__ w12pk,
                         short* __restrict__ whpk) {
    int t = blockIdx.x * 256 + threadIdx.x;
    const int NW3 = NKT * 5 * 64, NW12 = NKT * 10 * 64, NWH = 10 * 5 * 64;
    if (t < NW3) {
        int l = t & 63, nt = (t >> 6) % 5, kt = t / 320;
        int k0 = kt * 16 + (l >> 5) * 8, f = (l & 31) + nt * 32;
        bf16x8 pk;
        #pragma unroll
        for (int u = 0; u < 8; ++u) {
            int k = k0 + u;
            pk[u] = (k < D_ && f < F_) ? f2b(win[((size_t)(2 * D_) + k) * F_ + f]) : (short)0;
        }
        *(bf16x8*)(w3pk + (size_t)t * 8) = pk;
    } else if (t < NW3 + NW12) {
        int t2 = t - NW3;
        int l = t2 & 63, nt = (t2 >> 6) % 10, kt = t2 / 640;
        int k0 = kt * 16 + (l >> 5) * 8, c = (l & 31) + nt * 32;
        bf16x8 pk;
        #pragma unroll
        for (int u = 0; u < 8; ++u) {
            int k = k0 + u;
            float val = 0.f;
            if (k < D_) {
                if (c < FP_) { if (c < F_) val = win[(size_t)k * F_ + c]; }
                else { int f = c - FP_; if (f < F_) val = win[((size_t)D_ + k) * F_ + f]; }
            }
            pk[u] = f2b(val);
        }
        *(bf16x8*)(w12pk + (size_t)t2 * 8) = pk;
    } else if (t < NW3 + NW12 + NWH) {
        int t3 = t - NW3 - NW12;
        int l = t3 & 63, nt = (t3 >> 6) % 5, kt = t3 / 320;
        int k0 = kt * 16 + (l >> 5) * 8, f = (l & 31) + nt * 32;
        bf16x8 pk;
        #pragma unroll
        for (int u = 0; u < 8; ++u) {
            int k = k0 + u;
            pk[u] = (k < F_ && f < F_) ? f2b(wh[(size_t)k * F_ + f]) : (short)0;
        }
        *(bf16x8*)(whpk + (size_t)t3 * 8) = pk;
    }
}

// ---------- P1 = E@W1 , P2 = E@W2 + b_in  (padded to FP_ cols) ----------
__global__ __launch_bounds__(256) void k_p12(const short* __restrict__ eapk,
                                             const short* __restrict__ w12pk,
                                             const float* __restrict__ bin,
                                             float* __restrict__ p1, float* __restrict__ p2) {
    int s = blockIdx.x / 5, ng = blockIdx.x % 5;
    int tid = threadIdx.x, lane = tid & 63, w = tid >> 6;
    int mt = w & 1, nt = ng * 2 + (w >> 1);
    f32x16 acc;
    #pragma unroll
    for (int r = 0; r < 16; ++r) acc[r] = 0.f;
    const size_t abase = (size_t)s * NKT * 2 * 64 * 8;
    #pragma unroll 4
    for (int kt = 0; kt < NKT; ++kt) {
        bf16x8 a = *(const bf16x8*)(eapk + abase + ((size_t)kt * 2 + mt) * 64 * 8 + (size_t)lane * 8);
        bf16x8 b = *(const bf16x8*)(w12pk + ((size_t)(kt * 10 + nt) * 64 + lane) * 8);
        acc = __builtin_amdgcn_mfma_f32_32x32x16_bf16(a, b, acc, 0, 0, 0);
    }
    int c = (lane & 31) + nt * 32;
    #pragma unroll
    for (int r = 0; r < 16; ++r) {
        int i = (r & 3) + 8 * (r >> 2) + 4 * (lane >> 5) + mt * 32;
        if (c < FP_) {
            p1[(size_t)(s * N_ + i) * FP_ + c] = acc[r];
        } else {
            int f = c - FP_;
            float bv = (f < F_) ? bin[f] : 0.f;
            p2[(size_t)(s * N_ + i) * FP_ + f] = acc[r] + bv;
        }
    }
}

// ---------- main fused kernel: per (s, group of 4 j) ----------
__global__ __launch_bounds__(256, 1) void k_main(
    const float* __restrict__ emb, const float* __restrict__ esc,
    const short* __restrict__ eapk, const short* __restrict__ w3pk,
    const short* __restrict__ whpk,
    const float* __restrict__ p1g, const float* __restrict__ p2g,
    const float* __restrict__ bhv, const float* __restrict__ wout,
    const float* __restrict__ bout,
    const int* __restrict__ labels, const int* __restrict__ nump,
    float* __restrict__ out) {

    __shared__ char lds[128872];
    short* hB   = (short*)lds;                  // [64][172] bf16 (phase2, overlaps ejB)
    float* ejB  = (float*)lds;                  // [4][1280]  (phase1)
    float* p2B  = (float*)(lds + 22016);        // [4][160]
    char*  stg  = lds + 24576;                  // 2 x 28672 (EA 8192 | W3 20480)
    float* h2B  = (float*)(lds + 24576);        // [64][150] (phase2, overlaps stg)
    float* p1B  = (float*)(lds + 81920);        // [64][160]
    float* sbuf = (float*)(lds + 122880);       // [64][7]
    float* wob  = (float*)(lds + 124672);       // [150*7]

    const int tid = threadIdx.x, lane = tid & 63, w = tid >> 6;
    const int bid = blockIdx.x, s = bid >> 4, j0 = (bid & 15) * 4;

    // ---- prestage: ej rows (padded), p2 slice, p1 slice, Wout ----
    for (int idx = tid; idx < 4 * KP_; idx += 256) {
        int jj = idx / KP_, k = idx - jj * KP_;
        ejB[idx] = (k < D_) ? emb[(size_t)(s * N_ + j0 + jj) * D_ + k] : 0.f;
    }
    for (int idx = tid; idx < 4 * FP_; idx += 256)
        p2B[idx] = p2g[(size_t)(s * N_ + j0) * FP_ + idx];
    for (int idx = tid; idx < N_ * FP_; idx += 256)
        p1B[idx] = p1g[(size_t)(s * N_) * FP_ + idx];
    for (int idx = tid; idx < F_ * 7; idx += 256)
        wob[idx] = wout[idx];

    f32x16 acc[2][5];
    #pragma unroll
    for (int mt = 0; mt < 2; ++mt)
        #pragma unroll
        for (int nt = 0; nt < 5; ++nt)
            #pragma unroll
            for (int r = 0; r < 16; ++r) acc[mt][nt][r] = 0.f;

    const char* easrc = (const char*)(eapk + (size_t)s * 81920);  // 163840 B per s
    const char* w3src = (const char*)w3pk;

    // prologue stage of superstep 0 (4 ktiles = 8192B EA + 20480B W3)
    float4 rg[7];
    {
        const char* ea = easrc;
        rg[0] = *(const float4*)(ea + w * 1024 + (lane << 4));
        rg[1] = *(const float4*)(ea + (4 + w) * 1024 + (lane << 4));
        #pragma unroll
        for (int m = 0; m < 5; ++m)
            rg[2 + m] = *(const float4*)(w3src + (m * 4 + w) * 1024 + (lane << 4));
        char* dst = stg;
        *(float4*)(dst + w * 1024 + (lane << 4)) = rg[0];
        *(float4*)(dst + (4 + w) * 1024 + (lane << 4)) = rg[1];
        #pragma unroll
        for (int m = 0; m < 5; ++m)
            *(float4*)(dst + 8192 + (m * 4 + w) * 1024 + (lane << 4)) = rg[2 + m];
    }
    __syncthreads();

    // ---- GEMM1: 20 supersteps x 4 ktiles, double-buffered ----
    #pragma unroll 1
    for (int ss = 0; ss < 20; ++ss) {
        float4 rn[7];
        if (ss + 1 < 20) {   // T14: issue next-tile loads early
            const char* ea = easrc + (size_t)(ss + 1) * 8192;
            rn[0] = *(const float4*)(ea + w * 1024 + (lane << 4));
            rn[1] = *(const float4*)(ea + (4 + w) * 1024 + (lane << 4));
            const char* ws3 = w3src + (size_t)(ss + 1) * 20480;
            #pragma unroll
            for (int m = 0; m < 5; ++m)
                rn[2 + m] = *(const float4*)(ws3 + (m * 4 + w) * 1024 + (lane << 4));
        }
        const char* bb = stg + (ss & 1) * 28672;
        #pragma unroll
        for (int kk = 0; kk < 4; ++kk) {
            const float* ejp = ejB + w * KP_ + (ss * 4 + kk) * 16 + ((lane >> 5) << 3);
            float4 e0 = *(const float4*)ejp;
            float4 e1 = *(const float4*)(ejp + 4);
            float ev[8] = {e0.x, e0.y, e0.z, e0.w, e1.x, e1.y, e1.z, e1.w};
            bf16x8 bfr[5];
            #pragma unroll
            for (int nt = 0; nt < 5; ++nt)
                bfr[nt] = *(const bf16x8*)(bb + 8192 + kk * 5120 + nt * 1024 + (lane << 4));
            #pragma unroll
            for (int mt = 0; mt < 2; ++mt) {
                uint4 eu = *(const uint4*)(bb + kk * 2048 + mt * 1024 + (lane << 4));
                uint32_t ew[4] = {eu.x, eu.y, eu.z, eu.w};
                union { uint32_t u[4]; bf16x8 v; } av;
                #pragma unroll
                for (int p = 0; p < 4; ++p) {
                    float flo = __uint_as_float(ew[p] << 16) * ev[2 * p];
                    float fhi = __uint_as_float(ew[p] & 0xffff0000u) * ev[2 * p + 1];
                    uint32_t pk;
                    asm("v_cvt_pk_bf16_f32 %0, %1, %2" : "=v"(pk) : "v"(flo), "v"(fhi));
                    av.u[p] = pk;
                }
                #pragma unroll
                for (int nt = 0; nt < 5; ++nt)
                    acc[mt][nt] = __builtin_amdgcn_mfma_f32_32x32x16_bf16(av.v, bfr[nt], acc[mt][nt], 0, 0, 0);
            }
        }
        if (ss + 1 < 20) {   // write next tile into other buffer
            char* dst = stg + ((ss + 1) & 1) * 28672;
            *(float4*)(dst + w * 1024 + (lane << 4)) = rn[0];
            *(float4*)(dst + (4 + w) * 1024 + (lane << 4)) = rn[1];
            #pragma unroll
            for (int m = 0; m < 5; ++m)
                *(float4*)(dst + 8192 + (m * 4 + w) * 1024 + (lane << 4)) = rn[2 + m];
        }
        __syncthreads();
    }

    // ---- phase 2: per-j serial: h -> GEMM2 -> GEMM3 -> CE epilogue ----
    for (int jj = 0; jj < 4; ++jj) {
        if (w == jj) {   // owner wave writes h = acc + P1[i] + P2[j]  (bf16, stride 172)
            #pragma unroll
            for (int mt = 0; mt < 2; ++mt)
                #pragma unroll
                for (int nt = 0; nt < 5; ++nt) {
                    int f = (lane & 31) + nt * 32;
                    float p2v = p2B[jj * FP_ + f];
                    #pragma unroll
                    for (int r = 0; r < 16; ++r) {
                        int i = (r & 3) + 8 * (r >> 2) + 4 * (lane >> 5) + mt * 32;
                        float hv = acc[mt][nt][r] + p1B[i * FP_ + f] + p2v;
                        hB[i * 172 + f] = f2b(hv);
                    }
                }
        }
        __syncthreads();

        // GEMM2: h2 = h @ Wh + bh ; tiles t = w, w+4, w+8
        f32x16 acc2[3];
        #pragma unroll
        for (int c = 0; c < 3; ++c)
            #pragma unroll
            for (int r = 0; r < 16; ++r) acc2[c][r] = 0.f;
        for (int kt = 0; kt < 10; ++kt) {
            #pragma unroll
            for (int c = 0; c < 3; ++c) {
                int t = w + c * 4;
                if (t >= 10) break;
                int mt = t / 5, nt = t - mt * 5;
                const short* ap = hB + ((lane & 31) + mt * 32) * 172 + kt * 16 + ((lane >> 5) << 3);
                short4 alo = *(const short4*)ap;
                short4 ahi = *(const short4*)(ap + 4);
                union { short sh[8]; bf16x8 v; } av;
                av.sh[0] = alo.x; av.sh[1] = alo.y; av.sh[2] = alo.z; av.sh[3] = alo.w;
                av.sh[4] = ahi.x; av.sh[5] = ahi.y; av.sh[6] = ahi.z; av.sh[7] = ahi.w;
                bf16x8 b = *(const bf16x8*)(whpk + ((size_t)(kt * 5 + nt) * 64 + lane) * 8);
                acc2[c] = __builtin_amdgcn_mfma_f32_32x32x16_bf16(av.v, b, acc2[c], 0, 0, 0);
            }
        }
        #pragma unroll
        for (int c = 0; c < 3; ++c) {
            int t = w + c * 4;
            if (t >= 10) break;
            int mt = t / 5, nt = t - mt * 5;
            int f = (lane & 31) + nt * 32;
            if (f < F_) {
                float bhf = bhv[f];
                #pragma unroll
                for (int r = 0; r < 16; ++r) {
                    int i = (r & 3) + 8 * (r >> 2) + 4 * (lane >> 5) + mt * 32;
                    h2B[i * F_ + f] = acc2[c][r] + bhf;
                }
            }
        }
        __syncthreads();

        // GEMM3: scores = h2 @ Wout + bout  (f32 VALU, Wout in LDS)
        {
            const int i3 = tid & 63, lg = tid >> 6;
            const int l0 = lg, l1 = lg + 4;
            float s0 = bout[l0];
            float s1 = (l1 < 7) ? bout[l1] : 0.f;
            const float* hrow = h2B + i3 * F_;
            #pragma unroll 2
            for (int k = 0; k < F_; ++k) {
                const float hv = hrow[k];
                s0 += hv * wob[k * 7 + l0];
                if (l1 < 7) s1 += hv * wob[k * 7 + l1];
            }
            sbuf[i3 * 7 + l0] = s0;
            if (l1 < 7) sbuf[i3 * 7 + l1] = s1;
        }
        __syncthreads();

        // epilogue: rel_scores write + log-softmax CE + masked loss
        if (tid < 64) {
            const int i = tid, j = j0 + jj;
            const float esi = esc[s * N_ + i];
            const float esj = esc[s * N_ + j];
            float r[8];
            r[0] = 0.f;
            #pragma unroll
            for (int l = 1; l < 8; ++l) r[l] = sbuf[i * 7 + (l - 1)] + esi + esj;

            float4* op = (float4*)(out + ((size_t)(s * N_ + i) * N_ + j) * 8);
            op[0] = make_float4(r[0], r[1], r[2], r[3]);
            op[1] = make_float4(r[4], r[5], r[6], r[7]);

            float m = r[0];
            #pragma unroll
            for (int l = 1; l < 8; ++l) m = fmaxf(m, r[l]);
            float sum = 0.f;
            #pragma unroll
            for (int l = 0; l < 8; ++l) sum += expf(r[l] - m);
            const float lse = m + logf(sum);

            const int lab = labels[(s * N_ + i) * N_ + j];
            float ce = lse - r[lab];
            const int np = nump[s];
            float v = (i < np && j < np) ? ce : 0.f;
            #pragma unroll
            for (int off = 32; off; off >>= 1) v += __shfl_down(v, off);
            if (tid == 0) atomicAdd(out + LOSS_OFF, v);
        }
        __syncthreads();
    }
}

extern "C" void kernel_launch(void* const* d_in, const int* in_sizes, int n_in,
                              void* d_out, int out_size, void* d_ws, size_t ws_size,
                              hipStream_t stream) {
    const float* emb    = (const float*)d_in[0];
    const float* esc    = (const float*)d_in[1];
    const float* Win    = (const float*)d_in[2];
    const float* bin    = (const float*)d_in[3];
    const float* Wh     = (const float*)d_in[4];
    const float* bh     = (const float*)d_in[5];
    const float* Wout   = (const float*)d_in[6];
    const float* bout   = (const float*)d_in[7];
    const int*   labels = (const int*)d_in[8];
    const int*   nump   = (const int*)d_in[9];
    float* out = (float*)d_out;

    char* ws = (char*)d_ws;
    short* eapk  = (short*)(ws);
    short* w3pk  = (short*)(ws + 2621440);
    short* w12pk = (short*)(ws + 3031040);
    short* whpk  = (short*)(ws + 3850240);
    float* p1    = (float*)(ws + 3901440);
    float* p2    = (float*)(ws + 4556800);

    hipMemsetAsync(out + LOSS_OFF, 0, sizeof(float), stream);

    k_pack_ea<<<(S_ * NKT * 2 * 64 + 255) / 256, 256, 0, stream>>>(emb, eapk);
    k_pack_w<<<(NKT * 5 * 64 + NKT * 10 * 64 + 10 * 5 * 64 + 255) / 256, 256, 0, stream>>>(
        Win, Wh, w3pk, w12pk, whpk);
    k_p12<<<80, 256, 0, stream>>>(eapk, w12pk, bin, p1, p2);
    k_main<<<S_ * 16, 256, 0, stream>>>(emb, esc, eapk, w3pk, whpk, p1, p2,
                                        bh, Wout, bout, labels, nump, out);
}

// Round 3
// 134.833 us; speedup vs baseline: 9.2297x; 1.3758x over previous
//
#include <hip/hip_runtime.h>
#include <hip/hip_bf16.h>
#include <stdint.h>

typedef __attribute__((ext_vector_type(8))) short bf16x8;
typedef __attribute__((ext_vector_type(16))) float f32x16;

#define S_ 16
#define N_ 64
#define D_ 1270
#define F_ 150
#define KP_ 1280
#define FP_ 160
#define NKT 80
#define LOSS_OFF (S_*N_*N_*8)

#define HSTR 172     // hB row stride (bf16)
#define H2STR 161    // h2B row stride (f32), odd => conflict-free column reads

// ---------- helpers ----------
__device__ inline short f2b(float x) {              // f32 -> bf16 (RNE)
    union { float f; uint32_t u; } v; v.f = x;
    uint32_t r = (v.u + 0x7fffu + ((v.u >> 16) & 1u)) >> 16;
    return (short)r;
}

// ---------- fused pack: E -> A-frag, W3/[W1|W2]/Wh -> B-frag (bf16) ----------
__global__ void k_pack(const float* __restrict__ emb, const float* __restrict__ win,
                       const float* __restrict__ wh,
                       short* __restrict__ eapk, short* __restrict__ w3pk,
                       short* __restrict__ w12pk, short* __restrict__ whpk) {
    int t = blockIdx.x * 256 + threadIdx.x;
    const int TOT_EA = S_ * NKT * 2 * 64;
    const int NW3 = NKT * 5 * 64, NW12 = NKT * 10 * 64, NWH = 10 * 5 * 64;
    if (t < TOT_EA) {
        int l  = t & 63;
        int mt = (t >> 6) & 1;
        int kt = (t >> 7) % NKT;
        int s  = t / (NKT * 2 * 64);
        int i  = (l & 31) + mt * 32;
        int k0 = kt * 16 + (l >> 5) * 8;
        const float* src = emb + (size_t)(s * N_ + i) * D_;
        bf16x8 pk;
        #pragma unroll
        for (int u = 0; u < 8; ++u) {
            int k = k0 + u;
            pk[u] = (k < D_) ? f2b(src[k]) : (short)0;
        }
        *(bf16x8*)(eapk + (size_t)t * 8) = pk;
        return;
    }
    int t0 = t - TOT_EA;
    if (t0 < NW3) {
        int l = t0 & 63, nt = (t0 >> 6) % 5, kt = t0 / 320;
        int k0 = kt * 16 + (l >> 5) * 8, f = (l & 31) + nt * 32;
        bf16x8 pk;
        #pragma unroll
        for (int u = 0; u < 8; ++u) {
            int k = k0 + u;
            pk[u] = (k < D_ && f < F_) ? f2b(win[((size_t)(2 * D_) + k) * F_ + f]) : (short)0;
        }
        *(bf16x8*)(w3pk + (size_t)t0 * 8) = pk;
    } else if (t0 < NW3 + NW12) {
        int t2 = t0 - NW3;
        int l = t2 & 63, nt = (t2 >> 6) % 10, kt = t2 / 640;
        int k0 = kt * 16 + (l >> 5) * 8, c = (l & 31) + nt * 32;
        bf16x8 pk;
        #pragma unroll
        for (int u = 0; u < 8; ++u) {
            int k = k0 + u;
            float val = 0.f;
            if (k < D_) {
                if (c < FP_) { if (c < F_) val = win[(size_t)k * F_ + c]; }
                else { int f = c - FP_; if (f < F_) val = win[((size_t)D_ + k) * F_ + f]; }
            }
            pk[u] = f2b(val);
        }
        *(bf16x8*)(w12pk + (size_t)t2 * 8) = pk;
    } else if (t0 < NW3 + NW12 + NWH) {
        int t3 = t0 - NW3 - NW12;
        int l = t3 & 63, nt = (t3 >> 6) % 5, kt = t3 / 320;
        int k0 = kt * 16 + (l >> 5) * 8, f = (l & 31) + nt * 32;
        bf16x8 pk;
        #pragma unroll
        for (int u = 0; u < 8; ++u) {
            int k = k0 + u;
            pk[u] = (k < F_ && f < F_) ? f2b(wh[(size_t)k * F_ + f]) : (short)0;
        }
        *(bf16x8*)(whpk + (size_t)t3 * 8) = pk;
    }
}

// ---------- P1 = E@W1 , P2 = E@W2 + b_in : 320 independent 1-wave blocks ----------
__global__ __launch_bounds__(64) void k_p12(const short* __restrict__ eapk,
                                            const short* __restrict__ w12pk,
                                            const float* __restrict__ bin,
                                            float* __restrict__ p1, float* __restrict__ p2) {
    int bid = blockIdx.x;
    int s = bid / 20, rr = bid % 20;
    int nt = rr >> 1, mt = rr & 1;
    int lane = threadIdx.x;
    f32x16 acc;
    #pragma unroll
    for (int r = 0; r < 16; ++r) acc[r] = 0.f;
    const size_t abase = (size_t)s * NKT * 2 * 64 * 8;
    #pragma unroll 8
    for (int kt = 0; kt < NKT; ++kt) {
        bf16x8 a = *(const bf16x8*)(eapk + abase + ((size_t)kt * 2 + mt) * 64 * 8 + (size_t)lane * 8);
        bf16x8 b = *(const bf16x8*)(w12pk + ((size_t)(kt * 10 + nt) * 64 + lane) * 8);
        acc = __builtin_amdgcn_mfma_f32_32x32x16_bf16(a, b, acc, 0, 0, 0);
    }
    int c = (lane & 31) + nt * 32;
    #pragma unroll
    for (int r = 0; r < 16; ++r) {
        int i = (r & 3) + 8 * (r >> 2) + 4 * (lane >> 5) + mt * 32;
        if (c < FP_) {
            p1[(size_t)(s * N_ + i) * FP_ + c] = acc[r];
        } else {
            int f = c - FP_;
            float bv = (f < F_) ? bin[f] : 0.f;
            p2[(size_t)(s * N_ + i) * FP_ + f] = acc[r] + bv;
        }
    }
}

// ---------- main fused kernel: block = (s, 4 j's), 8 waves = (jj x mt) ----------
__global__ __launch_bounds__(512, 2) void k_main(
    const float* __restrict__ emb, const float* __restrict__ esc,
    const short* __restrict__ eapk, const short* __restrict__ w3pk,
    const short* __restrict__ whpk,
    const float* __restrict__ p1g, const float* __restrict__ p2g,
    const float* __restrict__ bhv, const float* __restrict__ wout,
    const float* __restrict__ bout,
    const int* __restrict__ labels, const int* __restrict__ nump,
    float* __restrict__ out) {

    __shared__ char lds[134656];
    float* wob  = (float*)lds;                 // [150*7]
    float* sbuf = (float*)(lds + 4224);        // [2][64*7]
    // union region:
    float* ejB  = (float*)(lds + 8192);        // GEMM1: [4][1280] f32
    char*  stg  = lds + 28672;                 // GEMM1: 2 x 28672 (EA 8KB | W3 20KB)
    short* hB   = (short*)(lds + 8192);        // phase2: [2][64*HSTR] bf16
    float* h2B  = (float*)(lds + 52224);       // phase2: [2][64*H2STR] f32

    const int tid = threadIdx.x, lane = tid & 63, w = tid >> 6;
    const int jj = w >> 1, mt = w & 1;
    const int bid = blockIdx.x, s = bid >> 4, j0 = (bid & 15) * 4;

    // ---- prologue: ej rows (f32, padded), Wout, superstep-0 stage ----
    for (int idx = tid; idx < 4 * KP_; idx += 512) {
        int jr = idx / KP_, k = idx - jr * KP_;
        ejB[idx] = (k < D_) ? emb[(size_t)(s * N_ + j0 + jr) * D_ + k] : 0.f;
    }
    for (int idx = tid; idx < F_ * 7; idx += 512) wob[idx] = wout[idx];

    const char* easrc = (const char*)eapk + (size_t)s * 163840;
    const char* w3src = (const char*)w3pk;
    {
        float4 r0 = *(const float4*)(easrc + (size_t)tid * 16);
        float4 r1 = *(const float4*)(w3src + (size_t)tid * 16);
        float4 r2 = *(const float4*)(w3src + 8192 + (size_t)tid * 16);
        float4 r3;
        if (tid < 256) r3 = *(const float4*)(w3src + 16384 + (size_t)tid * 16);
        char* dst = stg;
        *(float4*)(dst + tid * 16) = r0;
        *(float4*)(dst + 8192 + tid * 16) = r1;
        *(float4*)(dst + 16384 + tid * 16) = r2;
        if (tid < 256) *(float4*)(dst + 24576 + tid * 16) = r3;
    }
    __syncthreads();

    f32x16 acc[5];
    #pragma unroll
    for (int nt = 0; nt < 5; ++nt)
        #pragma unroll
        for (int r = 0; r < 16; ++r) acc[nt][r] = 0.f;

    // ---- GEMM1: 20 supersteps x 4 ktiles, double-buffered, T14 ----
    #pragma unroll 1
    for (int ss = 0; ss < 20; ++ss) {
        float4 r0, r1, r2, r3;
        if (ss + 1 < 20) {   // issue next-superstep loads early
            const char* ea = easrc + (size_t)(ss + 1) * 8192;
            const char* w3 = w3src + (size_t)(ss + 1) * 20480;
            r0 = *(const float4*)(ea + (size_t)tid * 16);
            r1 = *(const float4*)(w3 + (size_t)tid * 16);
            r2 = *(const float4*)(w3 + 8192 + (size_t)tid * 16);
            if (tid < 256) r3 = *(const float4*)(w3 + 16384 + (size_t)tid * 16);
        }
        const char* bb = stg + (ss & 1) * 28672;
        #pragma unroll
        for (int kk = 0; kk < 4; ++kk) {
            const float* ejp = ejB + jj * KP_ + (ss * 4 + kk) * 16 + ((lane >> 5) << 3);
            float4 e0 = *(const float4*)ejp;
            float4 e1 = *(const float4*)(ejp + 4);
            float ev[8] = {e0.x, e0.y, e0.z, e0.w, e1.x, e1.y, e1.z, e1.w};
            uint4 eu = *(const uint4*)(bb + kk * 2048 + mt * 1024 + (lane << 4));
            uint32_t ew[4] = {eu.x, eu.y, eu.z, eu.w};
            union { uint32_t u[4]; bf16x8 v; } av;
            #pragma unroll
            for (int p = 0; p < 4; ++p) {
                float flo = __uint_as_float(ew[p] << 16) * ev[2 * p];
                float fhi = __uint_as_float(ew[p] & 0xffff0000u) * ev[2 * p + 1];
                uint32_t pk;
                asm("v_cvt_pk_bf16_f32 %0, %1, %2" : "=v"(pk) : "v"(flo), "v"(fhi));
                av.u[p] = pk;
            }
            #pragma unroll
            for (int nt = 0; nt < 5; ++nt) {
                bf16x8 bfr = *(const bf16x8*)(bb + 8192 + kk * 5120 + nt * 1024 + (lane << 4));
                acc[nt] = __builtin_amdgcn_mfma_f32_32x32x16_bf16(av.v, bfr, acc[nt], 0, 0, 0);
            }
        }
        if (ss + 1 < 20) {   // write next superstep into other buffer
            char* dst = stg + ((ss + 1) & 1) * 28672;
            *(float4*)(dst + tid * 16) = r0;
            *(float4*)(dst + 8192 + tid * 16) = r1;
            *(float4*)(dst + 16384 + tid * 16) = r2;
            if (tid < 256) *(float4*)(dst + 24576 + tid * 16) = r3;
        }
        __syncthreads();
    }

    // ---- phase 2: two rounds of 2 j's, all 8 waves busy in GEMM2 ----
    for (int r2i = 0; r2i < 2; ++r2i) {
        if ((w >> 2) == r2i) {   // 4 writer waves: jl=(w>>1)&1, this mt half
            int jl = (w >> 1) & 1;
            int j = j0 + r2i * 2 + jl;
            #pragma unroll
            for (int nt = 0; nt < 5; ++nt) {
                int f = (lane & 31) + nt * 32;
                float p2v = p2g[(size_t)(s * N_ + j) * FP_ + f];
                #pragma unroll
                for (int r = 0; r < 16; ++r) {
                    int i = (r & 3) + 8 * (r >> 2) + 4 * (lane >> 5) + mt * 32;
                    float hv = acc[nt][r] + p1g[(size_t)(s * N_ + i) * FP_ + f] + p2v;
                    hB[jl * (64 * HSTR) + i * HSTR + f] = f2b(hv);
                }
            }
        }
        __syncthreads();

        // GEMM2: h2 = h @ Wh + bh ; 20 tiles over 8 waves
        {
            int jl2 = w >> 2, tt = w & 3;
            f32x16 acc2[3];
            #pragma unroll
            for (int c = 0; c < 3; ++c)
                #pragma unroll
                for (int r = 0; r < 16; ++r) acc2[c][r] = 0.f;
            const short* hbase = hB + jl2 * (64 * HSTR);
            for (int kt = 0; kt < 10; ++kt) {
                #pragma unroll
                for (int c = 0; c < 3; ++c) {
                    int t = tt + 4 * c;
                    if (t >= 10) break;
                    int mt2 = t / 5, nt2 = t - mt2 * 5;
                    const short* ap = hbase + ((lane & 31) + mt2 * 32) * HSTR + kt * 16 + ((lane >> 5) << 3);
                    short4 alo = *(const short4*)ap;
                    short4 ahi = *(const short4*)(ap + 4);
                    union { short sh[8]; bf16x8 v; } av;
                    av.sh[0] = alo.x; av.sh[1] = alo.y; av.sh[2] = alo.z; av.sh[3] = alo.w;
                    av.sh[4] = ahi.x; av.sh[5] = ahi.y; av.sh[6] = ahi.z; av.sh[7] = ahi.w;
                    bf16x8 b = *(const bf16x8*)(whpk + ((size_t)(kt * 5 + nt2) * 64 + lane) * 8);
                    acc2[c] = __builtin_amdgcn_mfma_f32_32x32x16_bf16(av.v, b, acc2[c], 0, 0, 0);
                }
            }
            #pragma unroll
            for (int c = 0; c < 3; ++c) {
                int t = tt + 4 * c;
                if (t >= 10) break;
                int mt2 = t / 5, nt2 = t - mt2 * 5;
                int f = (lane & 31) + nt2 * 32;
                if (f < F_) {
                    float bhf = bhv[f];
                    #pragma unroll
                    for (int r = 0; r < 16; ++r) {
                        int i = (r & 3) + 8 * (r >> 2) + 4 * (lane >> 5) + mt2 * 32;
                        h2B[jl2 * (64 * H2STR) + i * H2STR + f] = acc2[c][r] + bhf;
                    }
                }
            }
        }
        __syncthreads();

        // GEMM3: scores = h2 @ Wout + bout (VALU), both j's concurrently
        {
            int jl3 = tid >> 8;
            int i3 = tid & 63, lg = (tid >> 6) & 3;
            int l0 = lg, l1 = lg + 4;
            float s0 = bout[l0];
            float s1 = (l1 < 7) ? bout[l1] : 0.f;
            const float* hrow = h2B + jl3 * (64 * H2STR) + i3 * H2STR;
            #pragma unroll 2
            for (int k = 0; k < F_; ++k) {
                const float hv = hrow[k];
                s0 += hv * wob[k * 7 + l0];
                if (l1 < 7) s1 += hv * wob[k * 7 + l1];
            }
            sbuf[jl3 * 448 + i3 * 7 + l0] = s0;
            if (l1 < 7) sbuf[jl3 * 448 + i3 * 7 + l1] = s1;
        }
        __syncthreads();

        // epilogue: rel_scores write + log-softmax CE + masked loss (128 threads)
        if (tid < 128) {
            int jl = tid >> 6;
            int i = tid & 63;
            int j = j0 + r2i * 2 + jl;
            const float esi = esc[s * N_ + i];
            const float esj = esc[s * N_ + j];
            float rr[8];
            rr[0] = 0.f;
            #pragma unroll
            for (int l = 1; l < 8; ++l) rr[l] = sbuf[jl * 448 + i * 7 + (l - 1)] + esi + esj;

            float4* op = (float4*)(out + ((size_t)(s * N_ + i) * N_ + j) * 8);
            op[0] = make_float4(rr[0], rr[1], rr[2], rr[3]);
            op[1] = make_float4(rr[4], rr[5], rr[6], rr[7]);

            float m = rr[0];
            #pragma unroll
            for (int l = 1; l < 8; ++l) m = fmaxf(m, rr[l]);
            float sum = 0.f;
            #pragma unroll
            for (int l = 0; l < 8; ++l) sum += expf(rr[l] - m);
            const float lse = m + logf(sum);

            const int lab = labels[(s * N_ + i) * N_ + j];
            float ce = lse - rr[lab];
            const int np = nump[s];
            float v = (i < np && j < np) ? ce : 0.f;
            #pragma unroll
            for (int off = 32; off; off >>= 1) v += __shfl_down(v, off);
            if ((tid & 63) == 0) atomicAdd(out + LOSS_OFF, v);
        }
        __syncthreads();
    }
}

extern "C" void kernel_launch(void* const* d_in, const int* in_sizes, int n_in,
                              void* d_out, int out_size, void* d_ws, size_t ws_size,
                              hipStream_t stream) {
    const float* emb    = (const float*)d_in[0];
    const float* esc    = (const float*)d_in[1];
    const float* Win    = (const float*)d_in[2];
    const float* bin    = (const float*)d_in[3];
    const float* Wh     = (const float*)d_in[4];
    const float* bh     = (const float*)d_in[5];
    const float* Wout   = (const float*)d_in[6];
    const float* bout   = (const float*)d_in[7];
    const int*   labels = (const int*)d_in[8];
    const int*   nump   = (const int*)d_in[9];
    float* out = (float*)d_out;

    char* ws = (char*)d_ws;
    short* eapk  = (short*)(ws);
    short* w3pk  = (short*)(ws + 2621440);
    short* w12pk = (short*)(ws + 3031040);
    short* whpk  = (short*)(ws + 3850240);
    float* p1    = (float*)(ws + 3901440);
    float* p2    = (float*)(ws + 4556800);

    hipMemsetAsync(out + LOSS_OFF, 0, sizeof(float), stream);

    const int TOT_EA = S_ * NKT * 2 * 64;
    const int NW = NKT * 5 * 64 + NKT * 10 * 64 + 10 * 5 * 64;
    k_pack<<<(TOT_EA + NW + 255) / 256, 256, 0, stream>>>(emb, Win, Wh, eapk, w3pk, w12pk, whpk);
    k_p12<<<320, 64, 0, stream>>>(eapk, w12pk, bin, p1, p2);
    k_main<<<S_ * 16, 512, 0, stream>>>(emb, esc, eapk, w3pk, whpk, p1, p2,
                                        bh, Wout, bout, labels, nump, out);
}